// Round 1
// baseline (115.779 us; speedup 1.0000x reference)
//
#include <hip/hip_runtime.h>
#include <stdint.h>

#define NROWS 8192
#define DIM 128

typedef __bf16 bf16x8 __attribute__((ext_vector_type(8)));
typedef float floatx4 __attribute__((ext_vector_type(4)));

// ---------- helpers ----------
static __device__ __forceinline__ unsigned short f2bf(float f) {
    unsigned int u = __float_as_uint(f);
    unsigned int r = (u + 0x7FFFu + ((u >> 16) & 1u)) >> 16;   // RNE
    return (unsigned short)r;
}

// XOR swizzle on linear uint4 index g (per 512-uint4 chunk = 32 cols x 16 uint4):
// slot = (g&15) ^ (col&7). Bank group = 4*slot mod 32 -> 2-way only (free).
// Works unchanged for any chunk since XOR uses only (g>>4)&7 == col%8.
static __device__ __forceinline__ int swz(int g) {
    return (g & ~15) | ((g & 15) ^ ((g >> 4) & 7));
}

// ---------- kernel 1: normalize rows, emit bf16 a_hat + pos_dist + init max keys ----------
__global__ __launch_bounds__(256) void normalize_kernel(
    const float* __restrict__ anchor, const float* __restrict__ positive,
    unsigned short* __restrict__ a_hat, float* __restrict__ pos_ws,
    int* __restrict__ g_ws, float* __restrict__ out)
{
    if (blockIdx.x == 0 && threadIdx.x == 0) *out = 0.0f;   // replaces memset dispatch

    const int wave = threadIdx.x >> 6;
    const int lane = threadIdx.x & 63;
    const int row  = blockIdx.x * 4 + wave;

    const float2* arow = (const float2*)(anchor   + row * DIM);
    const float2* prow = (const float2*)(positive + row * DIM);
    float2 a = arow[lane];
    float2 p = prow[lane];

    float sa  = a.x * a.x + a.y * a.y;
    float sp  = p.x * p.x + p.y * p.y;
    float sap = a.x * p.x + a.y * p.y;
    #pragma unroll
    for (int off = 32; off; off >>= 1) {
        sa  += __shfl_xor(sa,  off);
        sp  += __shfl_xor(sp,  off);
        sap += __shfl_xor(sap, off);
    }
    float na  = fmaxf(sqrtf(sa), 1e-12f);
    float npn = fmaxf(sqrtf(sp), 1e-12f);
    float inv = 1.0f / na;

    ushort2 pack;
    pack.x = f2bf(a.x * inv);
    pack.y = f2bf(a.y * inv);
    ((ushort2*)a_hat)[row * 64 + lane] = pack;

    if (lane == 0) {
        pos_ws[row] = 2.0f - 2.0f * sap / (na * npn);
        g_ws[row]   = 0x3F800000;   // key for g = -1  (key = 2+g = 1.0f)
    }
}

// ---------- kernel 2: symmetric fused gram row-max with label mask ----------
// Upper-triangle tiling of the symmetric gram matrix: 256-row x 128-col tiles,
// rb in [0,32), cc in [2*rb, 64)  ->  1056 tiles (0.52x the full 2048).
// Each tile contributes BOTH row-maxes (256 rows over its 128 cols) and, since
// gram[i][j] == gram[j][i] bit-exactly, col-maxes (128 cols over its 256 rows)
// via an LDS col-max + one global atomicMax per col.  Duplicate pairs on
// diagonal-crossing tiles are harmless (max idempotent; label mask kills i==i).
// 4 waves x 64 rows each; whole 32 KB B tile staged once (zero barriers in the
// K loop); each 8 KB LDS B-read per wave now covers 2x the outputs of the old
// 32-row/wave layout.
__global__ __launch_bounds__(256, 3) void gram_kernel(
    const unsigned short* __restrict__ a_hat, const int* __restrict__ labels,
    int* __restrict__ g_ws)
{
    const int tid  = threadIdx.x;
    const int lane = tid & 63;
    const int wave = tid >> 6;
    const int quad = lane >> 4;
    const int l15  = lane & 15;

    // triangle map: cum(rb) = rb*(65-rb); solve + fixup
    const int bid = blockIdx.x;
    int rb = (int)((65.0f - sqrtf(4225.0f - 4.0f * (float)bid)) * 0.5f);
    while (rb * (65 - rb) > bid) --rb;
    while ((rb + 1) * (64 - rb) <= bid) ++rb;
    const int cc = bid - rb * (65 - rb) + 2 * rb;

    const int rowBase = rb * 256 + wave * 64;   // this wave's 64 rows
    const int colBase = cc * 128;

    const uint4* A = (const uint4*)a_hat;       // row stride = 16 uint4 (256 B)

    __shared__ uint4 smem[2048];                // 32 KB: 128 cols x 16 uint4, swizzled
    __shared__ int   colmax[128];

    // issue B-tile stage loads first (needed for ds_write + barrier)
    uint4 st[8];
    #pragma unroll
    for (int i = 0; i < 8; ++i)
        st[i] = A[colBase * 16 + i * 256 + tid];

    if (tid < 128) colmax[tid] = (int)0x80000000;   // INT_MIN: loses to every key

    // A fragments: 64 rows = 4 slices of 16; lane holds A[l15][quad*8 k-chunk]
    bf16x8 afrag[4][4];
    #pragma unroll
    for (int ms = 0; ms < 4; ++ms) {
        const int r = rowBase + ms * 16 + l15;
        #pragma unroll
        for (int k = 0; k < 4; ++k)
            afrag[ms][k] = __builtin_bit_cast(bf16x8, A[r * 16 + k * 4 + quad]);
    }

    // output-row labels: row = rowBase + ms*16 + quad*4 + e  (int4-aligned)
    int4 rlab[4];
    #pragma unroll
    for (int ms = 0; ms < 4; ++ms)
        rlab[ms] = *(const int4*)(labels + rowBase + ms * 16 + quad * 4);

    #pragma unroll
    for (int i = 0; i < 8; ++i)
        smem[swz(i * 256 + tid)] = st[i];
    __syncthreads();

    float gmax[4][4];
    #pragma unroll
    for (int ms = 0; ms < 4; ++ms)
        #pragma unroll
        for (int e = 0; e < 4; ++e)
            gmax[ms][e] = -4.0f;

    #pragma unroll
    for (int cb = 0; cb < 4; ++cb) {
        const int C = colBase + cb * 32;
        const int clab0 = labels[C + l15];
        const int clab1 = labels[C + 16 + l15];

        bf16x8 bfrag[2][4];
        #pragma unroll
        for (int ns = 0; ns < 2; ++ns) {
            const int c = ns * 16 + l15;
            #pragma unroll
            for (int k = 0; k < 4; ++k) {
                const int g = cb * 512 + c * 16 + k * 4 + quad;
                bfrag[ns][k] = __builtin_bit_cast(bf16x8, smem[swz(g)]);
            }
        }

        #pragma unroll
        for (int ns = 0; ns < 2; ++ns) {
            const int cl = ns ? clab1 : clab0;
            float cmax = -4.0f;                    // col-max over this wave's 64 rows
            #pragma unroll
            for (int ms = 0; ms < 4; ++ms) {
                floatx4 acc = {0.f, 0.f, 0.f, 0.f};
                #pragma unroll
                for (int k = 0; k < 4; ++k)
                    acc = __builtin_amdgcn_mfma_f32_16x16x32_bf16(
                              afrag[ms][k], bfrag[ns][k], acc, 0, 0, 0);
                #pragma unroll
                for (int e = 0; e < 4; ++e) {
                    const int rle = (e == 0) ? rlab[ms].x : (e == 1) ? rlab[ms].y
                                  : (e == 2) ? rlab[ms].z : rlab[ms].w;
                    float v = (cl != rle) ? acc[e] : -4.0f;
                    gmax[ms][e] = fmaxf(gmax[ms][e], v);
                    cmax        = fmaxf(cmax, v);
                }
            }
            // combine the 4 quads (rows) for this col = C + ns*16 + l15
            cmax = fmaxf(cmax, __shfl_xor(cmax, 16));
            cmax = fmaxf(cmax, __shfl_xor(cmax, 32));
            if (quad == 0)
                atomicMax(&colmax[cb * 32 + ns * 16 + l15],
                          __float_as_int(2.0f + cmax));
        }
    }

    // row flush: reduce over the 16 cols (l15) per fragment row, atomicMax per row
    #pragma unroll
    for (int ms = 0; ms < 4; ++ms) {
        #pragma unroll
        for (int e = 0; e < 4; ++e) {
            float v = gmax[ms][e];
            #pragma unroll
            for (int off = 1; off < 16; off <<= 1)
                v = fmaxf(v, __shfl_xor(v, off));
            if (l15 == 0)
                atomicMax(g_ws + rowBase + ms * 16 + quad * 4 + e,
                          __float_as_int(2.0f + v));   // keys > 0: int order ok
        }
    }

    // col flush: symmetric contribution g_ws[col] = max over this tile's rows
    __syncthreads();
    if (tid < 128) atomicMax(g_ws + colBase + tid, colmax[tid]);
}

// ---------- kernel 3: final loss + mean ----------
__global__ __launch_bounds__(256) void loss_kernel(
    const float* __restrict__ pos_ws, const int* __restrict__ g_ws,
    float* __restrict__ out)
{
    const int i = blockIdx.x * 256 + threadIdx.x;
    float g    = __int_as_float(g_ws[i]) - 2.0f;
    float neg  = fmaxf(2.0f - 2.0f * g, 0.0f);
    float loss = fmaxf(pos_ws[i] - neg + 0.5f, 0.0f);

    #pragma unroll
    for (int off = 32; off; off >>= 1)
        loss += __shfl_xor(loss, off);

    __shared__ float ws[4];
    if ((threadIdx.x & 63) == 0) ws[threadIdx.x >> 6] = loss;
    __syncthreads();
    if (threadIdx.x == 0) {
        float s = ws[0] + ws[1] + ws[2] + ws[3];
        atomicAdd(out, s * (1.0f / 8192.0f));
    }
}

extern "C" void kernel_launch(void* const* d_in, const int* in_sizes, int n_in,
                              void* d_out, int out_size, void* d_ws, size_t ws_size,
                              hipStream_t stream) {
    const float* anchor   = (const float*)d_in[0];
    const float* positive = (const float*)d_in[1];
    const int*   labels   = (const int*)d_in[2];
    float* out = (float*)d_out;

    char* ws = (char*)d_ws;
    unsigned short* a_hat  = (unsigned short*)ws;                       // 2 MiB
    float*          pos_ws = (float*)(ws + 2 * 1024 * 1024);            // 32 KiB
    int*            g_ws   = (int*)  (ws + 2 * 1024 * 1024 + 32 * 1024);// 32 KiB

    normalize_kernel<<<NROWS / 4, 256, 0, stream>>>(anchor, positive, a_hat, pos_ws, g_ws, out);
    gram_kernel<<<1056, 256, 0, stream>>>(a_hat, labels, g_ws);
    loss_kernel<<<NROWS / 256, 256, 0, stream>>>(pos_ws, g_ws, out);
}